// Round 11
// baseline (1268.712 us; speedup 1.0000x reference)
//
#include <hip/hip_runtime.h>

#define Bdim 64
#define Ndim 512
#define Hdim 2048
#define KSPLIT 8
#define NCHUNK 8
#define LNEPS 1e-5f
#define WMAT_ELEMS (Hdim * Hdim)
#define GRIDP 256u

typedef unsigned short u16;
typedef __attribute__((ext_vector_type(8))) short short8;
typedef __attribute__((ext_vector_type(4))) float f32x4;

__device__ __forceinline__ u16 f2bf(float f) {
    unsigned int u = __float_as_uint(f);
    return (u16)((u + 0x7FFFu + ((u >> 16) & 1u)) >> 16);
}
__device__ __forceinline__ float bf2f(u16 s) {
    return __uint_as_float(((unsigned int)s) << 16);
}

// ---- grid barrier (persistent 256-block kernels; 1 block/CU co-resident) ----
// One-shot counters (monotonic), zeroed by init node each launch -> replay-safe.
// R3 lesson: device fences are fine AT stage boundaries (pipeline drained);
// they were catastrophic only mid-stream.
__device__ __forceinline__ void gbar(unsigned* cnt) {
    __syncthreads();
    if (threadIdx.x == 0) {
        __threadfence();                       // release: flush XCD L2
        atomicAdd(cnt, 1u);
        while (__hip_atomic_load(cnt, __ATOMIC_RELAXED, __HIP_MEMORY_SCOPE_AGENT) < GRIDP) {
            __builtin_amdgcn_s_sleep(2);
        }
        __threadfence();                       // acquire: invalidate L1/L2
    }
    __syncthreads();
}

__global__ void init_k(unsigned* cnts) {
    if (threadIdx.x < 64) cnts[threadIdx.x] = 0u;
}

// ---- stage bodies (verbatim from the proven R7/R10 kernels) ----

// convert: virtual bid v in [0,6144): v<4096 direct Wt,Wl,Wg,Wo; else WpT,WlT.
__device__ void dev_convert(int v, const float* Wt, const float* Wl,
                            const float* Wg, const float* Wo, const float* Wp,
                            u16* dst, char* smRaw)
{
    float (*L)[65] = (float(*)[65])smRaw;
    const int t = threadIdx.x;
    if (v < 4096) {
        const int mid = v >> 10;
        const int tb  = v & 1023;
        const float* src = (mid == 0) ? Wt : (mid == 1) ? Wl : (mid == 2) ? Wg : Wo;
        u16* out = dst + (size_t)mid * WMAT_ELEMS;
        const size_t base = (size_t)tb * 4096 + (size_t)t * 16;
#pragma unroll
        for (int i = 0; i < 2; ++i) {
            float4 a = *(const float4*)(src + base + i * 8);
            float4 b = *(const float4*)(src + base + i * 8 + 4);
            short8 s;
            s[0] = (short)f2bf(a.x); s[1] = (short)f2bf(a.y);
            s[2] = (short)f2bf(a.z); s[3] = (short)f2bf(a.w);
            s[4] = (short)f2bf(b.x); s[5] = (short)f2bf(b.y);
            s[6] = (short)f2bf(b.z); s[7] = (short)f2bf(b.w);
            *(short8*)(out + base + i * 8) = s;
        }
    } else {
        const int mid = 4 + ((v - 4096) >> 10);
        const int tb  = (v - 4096) & 1023;
        const float* src = (mid == 4) ? Wp : Wl;
        u16* out = dst + (size_t)mid * WMAT_ELEMS;
        const int k0 = (tb & 31) * 64;
        const int o0 = (tb >> 5) * 64;
        const int row = t >> 2;
        const int cq  = t & 3;
        __syncthreads();                        // L reuse across iterations
#pragma unroll
        for (int i = 0; i < 4; ++i) {
            float4 v4 = *(const float4*)(src + (size_t)(k0 + row) * Hdim + o0 + cq * 16 + i * 4);
            *(float4*)(&L[row][cq * 16 + i * 4]) = v4;
        }
        __syncthreads();
        const int orow = t >> 2;
#pragma unroll
        for (int half = 0; half < 2; ++half) {
            short8 s;
#pragma unroll
            for (int i = 0; i < 8; ++i)
                s[i] = (short)f2bf(L[cq * 16 + half * 8 + i][orow]);
            *(short8*)(out + (size_t)(o0 + orow) * Hdim + k0 + cq * 16 + half * 8) = s;
        }
    }
}

// k-split MFMA gemv: part[ks][b][o] = sum_{k in ks} X[b,k]*W[o][k].
// All 256 blocks participate (8 ks x 32 o-tiles).
template<int XF32, int WF32>
__device__ void dev_gemv(const u16* X16, const float* Xf,
                         const u16* Wb, const float* Wf,
                         float* part, char* smRaw)
{
    short (*Xs)[72] = (short(*)[72])smRaw;
    short (*Ws)[72] = (short(*)[72])(smRaw + 64 * 72 * 2);
    const int t  = threadIdx.x;
    const int nt = blockIdx.x & 31;
    const int ks = blockIdx.x >> 5;
    const int o0 = nt * 64;
    const int kb = ks * 256;
    const int wv = t >> 6;
    const int ln = t & 63;
    const int xr = t & 63;
    const int xg = t >> 6;
    const int wn = t >> 2;
    const int wk = (t & 3) * 16;

    f32x4 acc[4];
#pragma unroll
    for (int i = 0; i < 4; ++i)
#pragma unroll
        for (int j = 0; j < 4; ++j) acc[i][j] = 0.f;

    uint4  qx[2];
    float4 px[4];
    uint4  qw[2];
    float4 pw[4];
    auto gload = [&](int k0) {
        if (!XF32) {
            qx[0] = *(const uint4*)(X16 + (size_t)xr * Hdim + k0 + xg * 16);
            qx[1] = *(const uint4*)(X16 + (size_t)xr * Hdim + k0 + xg * 16 + 8);
        } else {
#pragma unroll
            for (int i = 0; i < 4; ++i)
                px[i] = *(const float4*)(Xf + (size_t)xr * Hdim + k0 + xg * 16 + i * 4);
        }
        if (!WF32) {
            qw[0] = *(const uint4*)(Wb + (size_t)(o0 + wn) * Hdim + k0 + wk);
            qw[1] = *(const uint4*)(Wb + (size_t)(o0 + wn) * Hdim + k0 + wk + 8);
        } else {
#pragma unroll
            for (int i = 0; i < 4; ++i)
                pw[i] = *(const float4*)(Wf + (size_t)(o0 + wn) * Hdim + k0 + wk + i * 4);
        }
    };
    auto cvt8 = [](const float4& a, const float4& b) {
        short8 s;
        s[0] = (short)f2bf(a.x); s[1] = (short)f2bf(a.y);
        s[2] = (short)f2bf(a.z); s[3] = (short)f2bf(a.w);
        s[4] = (short)f2bf(b.x); s[5] = (short)f2bf(b.y);
        s[6] = (short)f2bf(b.z); s[7] = (short)f2bf(b.w);
        return s;
    };
    auto lstore = [&]() {
        if (!XF32) {
            *(uint4*)(&Xs[xr][xg * 16])     = qx[0];
            *(uint4*)(&Xs[xr][xg * 16 + 8]) = qx[1];
        } else {
            *(short8*)(&Xs[xr][xg * 16])     = cvt8(px[0], px[1]);
            *(short8*)(&Xs[xr][xg * 16 + 8]) = cvt8(px[2], px[3]);
        }
        if (!WF32) {
            *(uint4*)(&Ws[wn][wk])     = qw[0];
            *(uint4*)(&Ws[wn][wk + 8]) = qw[1];
        } else {
            *(short8*)(&Ws[wn][wk])     = cvt8(pw[0], pw[1]);
            *(short8*)(&Ws[wn][wk + 8]) = cvt8(pw[2], pw[3]);
        }
    };

    gload(kb);
    for (int c = 0; c < 4; ++c) {
        __syncthreads();
        lstore();
        __syncthreads();
        if (c < 3) gload(kb + (c + 1) * 64);
#pragma unroll
        for (int kstep = 0; kstep < 2; ++kstep) {
            const int kf = kstep * 32 + (ln >> 4) * 8;
            short8 af = *(const short8*)(&Xs[16 * wv + (ln & 15)][kf]);
#pragma unroll
            for (int n4 = 0; n4 < 4; ++n4) {
                short8 bf = *(const short8*)(&Ws[n4 * 16 + (ln & 15)][kf]);
                acc[n4] = __builtin_amdgcn_mfma_f32_16x16x32_bf16(af, bf, acc[n4], 0, 0, 0);
            }
        }
    }
#pragma unroll
    for (int n4 = 0; n4 < 4; ++n4) {
#pragma unroll
        for (int r = 0; r < 4; ++r) {
            const int brow = 16 * wv + (ln >> 4) * 4 + r;
            part[(size_t)(ks * 64 + brow) * Hdim + o0 + n4 * 16 + (ln & 15)] = acc[n4][r];
        }
    }
}

// combine (virtual 128 blocks -> guard bid<128)
template<int HASBIAS, int ACC, int FINAL>
__device__ void dev_combine(int bid, const float* part, const float* bias,
                            float* Y, u16* Y16, float* out, int has_loss)
{
    const int flat4 = bid * 256 + threadIdx.x;
    const size_t e  = (size_t)flat4 * 4;
    const int o     = (int)(e & (Hdim - 1));
    float4 v;
    if (HASBIAS) v = *(const float4*)(bias + o);
    else         v = make_float4(0.f, 0.f, 0.f, 0.f);
#pragma unroll
    for (int s = 0; s < KSPLIT; ++s) {
        float4 p = *(const float4*)(part + (size_t)s * (64 * Hdim) + e);
        v.x += p.x; v.y += p.y; v.z += p.z; v.w += p.w;
    }
    if (ACC) {
        float4 a = *(const float4*)(Y + e);
        v.x += a.x; v.y += a.y; v.z += a.z; v.w += a.w;
    }
    *(float4*)(Y + e) = v;
    ushort4 m;
    m.x = f2bf(v.x); m.y = f2bf(v.y); m.z = f2bf(v.z); m.w = f2bf(v.w);
    *(ushort4*)(Y16 + e) = m;
    if (FINAL) {
        *(float4*)(out + e) = v;
        if (has_loss && flat4 == 0) out[Bdim * Hdim] = 0.f;
    }
}

// fcomb: virtual 512 blocks; called twice per block.
__device__ void dev_fcomb(int v, const u16* up, const float* wm,
                          const float* wz, u16* u16out, char* smRaw)
{
    float* mm = (float*)smRaw;
    float* zz = mm + 64;
    float* ee = zz + 64;
    const int t  = threadIdx.x;
    const int b  = v >> 3;
    const int sl = v & 7;
    __syncthreads();                            // smem reuse between calls
    if (t < 64) { mm[t] = wm[b * 64 + t]; zz[t] = wz[b * 64 + t]; }
    __syncthreads();
    float mg = mm[0];
#pragma unroll
    for (int i = 1; i < 64; ++i) mg = fmaxf(mg, mm[i]);
    if (t < 64) ee[t] = expf(mm[t] - mg);
    __syncthreads();
    float Z = 0.f;
#pragma unroll
    for (int i = 0; i < 64; ++i) Z += zz[i] * ee[i];
    const float inv = 1.f / Z;
    const int col = sl * 256 + t;
    float a = 0.f;
#pragma unroll 8
    for (int ch = 0; ch < 64; ++ch)
        a += ee[ch] * bf2f(up[(size_t)(b * 64 + ch) * Hdim + col]);
    u16out[(size_t)b * Hdim + col] = f2bf(a * inv);
}

// ln_relu from partials (virtual 64 blocks -> guard bid<64)
__device__ void dev_ln(int b, const float* part, const float* bias,
                       u16* r16, char* smRaw)
{
    float* trow = (float*)smRaw;            // 2048 f32
    float* red  = trow + Hdim;              // 8 f32
    const int t = threadIdx.x;
    float sum = 0.f, sq = 0.f;
#pragma unroll
    for (int i = 0; i < 2; ++i) {
        int c = (i * 256 + t) * 4;
        float4 v = *(const float4*)(bias + c);
#pragma unroll
        for (int s = 0; s < KSPLIT; ++s) {
            float4 p = *(const float4*)(part + ((size_t)(s * 64 + b)) * Hdim + c);
            v.x += p.x; v.y += p.y; v.z += p.z; v.w += p.w;
        }
        *(float4*)(&trow[c]) = v;
        sum += v.x + v.y + v.z + v.w;
        sq  += v.x * v.x + v.y * v.y + v.z * v.z + v.w * v.w;
    }
#pragma unroll
    for (int off = 32; off; off >>= 1) {
        sum += __shfl_xor(sum, off, 64);
        sq  += __shfl_xor(sq,  off, 64);
    }
    if ((t & 63) == 0) { red[t >> 6] = sum; red[4 + (t >> 6)] = sq; }
    __syncthreads();
    sum = red[0] + red[1] + red[2] + red[3];
    sq  = red[4] + red[5] + red[6] + red[7];
    const float mu   = sum * (1.f / Hdim);
    const float var  = sq * (1.f / Hdim) - mu * mu;
    const float rstd = rsqrtf(var + LNEPS);
#pragma unroll
    for (int i = 0; i < 2; ++i) {
        int c = (i * 256 + t) * 4;
        float4 v = *(const float4*)(&trow[c]);
        ushort4 o;
        o.x = f2bf(fmaxf(0.f, (v.x - mu) * rstd));
        o.y = f2bf(fmaxf(0.f, (v.y - mu) * rstd));
        o.z = f2bf(fmaxf(0.f, (v.z - mu) * rstd));
        o.w = f2bf(fmaxf(0.f, (v.w - mu) * rstd));
        *(ushort4*)(r16 + (size_t)b * Hdim + c) = o;
    }
}

// ---- persistent megakernels (grid = 256 blocks, 1/CU) ----

// mega1: convert + A-gemv/combine + theta-chain (thetal combined f32)
__global__ __launch_bounds__(256)
void mega1(const float* clip, const float* Wc, const float* bc,
           const float* Wt, const float* Wl, const float* Wg,
           const float* Wo, const float* Wp, const float* bt,
           u16* Wbf, float* PA, float* A, u16* A16, float* scrY,
           u16* th16, u16* tp16, float* thetal, u16* junk16, unsigned* cnts)
{
    __shared__ char SM[18464];
    const int bid = blockIdx.x;
    u16* bWt  = Wbf;
    u16* bWpT = Wbf + (size_t)4 * WMAT_ELEMS;
    u16* bWlT = Wbf + (size_t)5 * WMAT_ELEMS;

    for (int it = 0; it < 24; ++it)
        dev_convert(it * 256 + bid, Wt, Wl, Wg, Wo, Wp, Wbf, SM);
    dev_gemv<1,1>(nullptr, clip, nullptr, Wc, PA, SM);   // independent of convert
    gbar(cnts + 0);
    if (bid < 128) dev_combine<1,0,0>(bid, PA, bc, A, A16, nullptr, 0);
    gbar(cnts + 1);                                       // also orders converts
    dev_gemv<0,0>(A16, nullptr, bWt, nullptr, PA, SM);
    gbar(cnts + 2);
    if (bid < 128) dev_combine<1,0,0>(bid, PA, bt, scrY, th16, nullptr, 0);
    gbar(cnts + 3);
    dev_gemv<0,0>(th16, nullptr, bWpT, nullptr, PA, SM);
    gbar(cnts + 4);
    if (bid < 128) dev_combine<0,0,0>(bid, PA, nullptr, scrY, tp16, nullptr, 0);
    gbar(cnts + 5);
    dev_gemv<0,0>(tp16, nullptr, bWlT, nullptr, PA, SM);
    gbar(cnts + 6);
    if (bid < 128) dev_combine<0,0,0>(bid, PA, nullptr, thetal, junk16, nullptr, 0);
}

// mega2: fcomb + s/t/ln/o + residual; NEXT: also next layer's theta-chain;
// FINAL: write out.
template<int NEXT, int FINAL>
__global__ __launch_bounds__(256)
void mega2(const u16* up, const float* wm, const float* wz, u16* ubuf,
           u16* Wbf, float* PA, const float* bl, float* scrY, u16* s16,
           const float* bg, u16* r16, const float* bo, float* A, u16* A16,
           float* out, int has_loss, const float* bt,
           u16* th16, u16* tp16, float* thetal, u16* junk16, unsigned* cnts)
{
    __shared__ char SM[18464];
    const int bid = blockIdx.x;
    u16* bWt  = Wbf;
    u16* bWl  = Wbf + (size_t)1 * WMAT_ELEMS;
    u16* bWg  = Wbf + (size_t)2 * WMAT_ELEMS;
    u16* bWo  = Wbf + (size_t)3 * WMAT_ELEMS;
    u16* bWpT = Wbf + (size_t)4 * WMAT_ELEMS;
    u16* bWlT = Wbf + (size_t)5 * WMAT_ELEMS;

    dev_fcomb(bid * 2 + 0, up, wm, wz, ubuf, SM);
    dev_fcomb(bid * 2 + 1, up, wm, wz, ubuf, SM);
    gbar(cnts + 0);
    dev_gemv<0,0>(ubuf, nullptr, bWl, nullptr, PA, SM);
    gbar(cnts + 1);
    if (bid < 128) dev_combine<1,0,0>(bid, PA, bl, scrY, s16, nullptr, 0);
    gbar(cnts + 2);
    dev_gemv<0,0>(s16, nullptr, bWg, nullptr, PA, SM);
    gbar(cnts + 3);
    if (bid < 64) dev_ln(bid, PA, bg, r16, SM);
    gbar(cnts + 4);
    dev_gemv<0,0>(r16, nullptr, bWo, nullptr, PA, SM);
    gbar(cnts + 5);
    if (bid < 128) dev_combine<1,1,FINAL>(bid, PA, bo, A, A16, out, has_loss);
    if (NEXT) {
        gbar(cnts + 6);
        dev_gemv<0,0>(A16, nullptr, bWt, nullptr, PA, SM);
        gbar(cnts + 7);
        if (bid < 128) dev_combine<1,0,0>(bid, PA, bt, scrY, th16, nullptr, 0);
        gbar(cnts + 8);
        dev_gemv<0,0>(th16, nullptr, bWpT, nullptr, PA, SM);
        gbar(cnts + 9);
        if (bid < 128) dev_combine<0,0,0>(bid, PA, nullptr, scrY, tp16, nullptr, 0);
        gbar(cnts + 10);
        dev_gemv<0,0>(tp16, nullptr, bWlT, nullptr, PA, SM);
        gbar(cnts + 11);
        if (bid < 128) dev_combine<0,0,0>(bid, PA, nullptr, thetal, junk16, nullptr, 0);
    }
}

// ---- flash (separate 4096-block node; R7-proven, reads COMBINED thetal) ----
template<int FIRST>
__global__ __launch_bounds__(256, 4)
void flash_chunk(const float* __restrict__ lfb, const u16* __restrict__ lfb16r,
                 u16* __restrict__ lfb16w, const float* __restrict__ thetal,
                 float scale, u16* __restrict__ up,
                 float* __restrict__ wm, float* __restrict__ wz)
{
    __shared__ u16 T[NCHUNK][Hdim];
    __shared__ float th[Hdim];
    __shared__ float sc[NCHUNK];
    __shared__ float wts[NCHUNK];
    const int t  = threadIdx.x;
    const int b  = blockIdx.x >> 6;
    const int ch = blockIdx.x & 63;
    const size_t nbase = (size_t)b * Ndim + ch * NCHUNK;
#pragma unroll
    for (int i = 0; i < 16; ++i) {
        int flat4 = i * 256 + t;
        int row   = flat4 >> 9;
        int c4    = flat4 & 511;
        if (FIRST) {
            float4 v = *(const float4*)(lfb + (nbase + row) * Hdim + c4 * 4);
            ushort4 u4;
            u4.x = f2bf(v.x); u4.y = f2bf(v.y); u4.z = f2bf(v.z); u4.w = f2bf(v.w);
            *(ushort4*)(&T[row][c4 * 4]) = u4;
            *(ushort4*)(lfb16w + (nbase + row) * Hdim + c4 * 4) = u4;
        } else {
            ushort4 u4 = *(const ushort4*)(lfb16r + (nbase + row) * Hdim + c4 * 4);
            *(ushort4*)(&T[row][c4 * 4]) = u4;
        }
    }
#pragma unroll
    for (int i = 0; i < 2; ++i) {
        int c = (i * 256 + t) * 4;
        float4 v = *(const float4*)(thetal + (size_t)b * Hdim + c);
        *(float4*)(&th[c]) = v;
    }
    __syncthreads();
    const int wv = t >> 6, ln = t & 63;
#pragma unroll
    for (int q = 0; q < 2; ++q) {
        int n = wv * 2 + q;
        float a = 0.f;
#pragma unroll
        for (int i = 0; i < 8; ++i) {
            int c = ln * 4 + i * 256;
            ushort4 x = *(const ushort4*)(&T[n][c]);
            float4 y  = *(const float4*)(&th[c]);
            a += bf2f(x.x) * y.x + bf2f(x.y) * y.y + bf2f(x.z) * y.z + bf2f(x.w) * y.w;
        }
#pragma unroll
        for (int off = 32; off; off >>= 1) a += __shfl_xor(a, off, 64);
        if (ln == 0) sc[n] = a * scale;
    }
    __syncthreads();
    float m = sc[0];
#pragma unroll
    for (int n = 1; n < NCHUNK; ++n) m = fmaxf(m, sc[n]);
    if (t < NCHUNK) wts[t] = expf(sc[t] - m);
    __syncthreads();
    if (t == 0) {
        float z = 0.f;
#pragma unroll
        for (int n = 0; n < NCHUNK; ++n) z += wts[n];
        wm[blockIdx.x] = m;
        wz[blockIdx.x] = z;
    }
#pragma unroll
    for (int i = 0; i < 8; ++i) {
        int c = t + i * 256;
        float a = 0.f;
#pragma unroll
        for (int n = 0; n < NCHUNK; ++n) a += wts[n] * bf2f(T[n][c]);
        up[(size_t)blockIdx.x * Hdim + c] = f2bf(a);
    }
}

extern "C" void kernel_launch(void* const* d_in, const int* in_sizes, int n_in,
                              void* d_out, int out_size, void* d_ws, size_t ws_size,
                              hipStream_t stream) {
    (void)in_sizes; (void)n_in; (void)ws_size;
    const float* clip = (const float*)d_in[0];
    const float* lfb  = (const float*)d_in[1];
    const float* Wc   = (const float*)d_in[2];
    const float* bc   = (const float*)d_in[3];
    const float* Wl   = (const float*)d_in[4];
    const float* bl   = (const float*)d_in[5];
    const float* Wt   = (const float*)d_in[6];
    const float* bt   = (const float*)d_in[7];
    const float* Wp   = (const float*)d_in[8];
    // d_in[9] = bp: cancels in softmax (per-row constant) -> unused
    const float* Wg   = (const float*)d_in[10];
    const float* bg   = (const float*)d_in[11];
    const float* Wo   = (const float*)d_in[12];
    const float* bo   = (const float*)d_in[13];
    float* out = (float*)d_out;

    // Workspace layout (f32 slots); u16 buffers counted in f32 slots.
    float*    wsf    = (float*)d_ws;
    float*    A      = wsf;                       // 131072
    float*    scrY   = wsf + 131072;              // 131072
    float*    thetal = wsf + 262144;              // 131072
    u16*      A16    = (u16*)(wsf + 393216);      // 65536 slots each
    u16*      th16   = (u16*)(wsf + 458752);
    u16*      tp16   = (u16*)(wsf + 524288);
    u16*      s16    = (u16*)(wsf + 589824);
    u16*      ubuf   = (u16*)(wsf + 655360);
    u16*      r16    = (u16*)(wsf + 720896);
    u16*      junk16 = (u16*)(wsf + 786432);
    float*    wm     = wsf + 851968;              // 4096
    float*    wz     = wsf + 856064;              // 4096
    unsigned* cnts   = (unsigned*)(wsf + 860160); // 64 slots
    float*    PA     = wsf + 860224;              // 1048576 -> 1908800
    u16*      up     = (u16*)(wsf + 1908800);     // 4194304 slots -> 6103104
    u16*      lfb16  = (u16*)(wsf + 6103104);     // 33554432 slots -> 39657536
    u16*      Wbf    = (u16*)(wsf + 39657536);    // 6*2097152 slots (~209 MB)

    const float scale = 0.022097086912079608f;    // 1/sqrt(2048)
    const int has_loss = (out_size > Bdim * Hdim) ? 1 : 0;
    dim3 blk(256);

    init_k<<<1, 64, 0, stream>>>(cnts);
    // prologue + layer-0 theta chain
    mega1<<<256, blk, 0, stream>>>(clip, Wc, bc, Wt, Wl, Wg, Wo, Wp, bt,
                                   Wbf, PA, A, A16, scrY, th16, tp16, thetal,
                                   junk16, cnts + 0);
    // layer 0
    flash_chunk<1><<<4096, blk, 0, stream>>>(lfb, nullptr, lfb16, thetal, scale, up, wm, wz);
    mega2<1,0><<<256, blk, 0, stream>>>(up, wm, wz, ubuf, Wbf, PA, bl, scrY, s16,
                                        bg, r16, bo, A, A16, nullptr, 0, bt,
                                        th16, tp16, thetal, junk16, cnts + 7);
    // layer 1
    flash_chunk<0><<<4096, blk, 0, stream>>>(nullptr, lfb16, nullptr, thetal, scale, up, wm, wz);
    mega2<1,0><<<256, blk, 0, stream>>>(up, wm, wz, ubuf, Wbf, PA, bl, scrY, s16,
                                        bg, r16, bo, A, A16, nullptr, 0, bt,
                                        th16, tp16, thetal, junk16, cnts + 19);
    // layer 2
    flash_chunk<0><<<4096, blk, 0, stream>>>(nullptr, lfb16, nullptr, thetal, scale, up, wm, wz);
    mega2<0,1><<<256, blk, 0, stream>>>(up, wm, wz, ubuf, Wbf, PA, bl, scrY, s16,
                                        bg, r16, bo, A, A16, out, has_loss, bt,
                                        th16, tp16, thetal, junk16, cnts + 31);
}

// Round 12
// 390.824 us; speedup vs baseline: 3.2462x; 3.2462x over previous
//
#include <hip/hip_runtime.h>

#define Bdim 64
#define Ndim 512
#define Hdim 2048
#define KSPLIT 8
#define NCHUNK 8
#define LNEPS 1e-5f
#define WMAT_ELEMS (Hdim * Hdim)

typedef unsigned short u16;
typedef __attribute__((ext_vector_type(8))) short short8;
typedef __attribute__((ext_vector_type(4))) float f32x4;

__device__ __forceinline__ u16 f2bf(float f) {
    unsigned int u = __float_as_uint(f);
    return (u16)((u + 0x7FFFu + ((u >> 16) & 1u)) >> 16);
}
__device__ __forceinline__ float bf2f(u16 s) {
    return __uint_as_float(((unsigned int)s) << 16);
}

// One-time weight prep -> 7 bf16 matrices, ALL in [o][k] layout (k contiguous):
// mid 0..4: direct convert of Wc,Wt,Wl,Wg,Wo
// mid 5: bWpT[o][k] = Wp[k*H+o]; mid 6: bWlT[o][k] = Wl[k*H+o]
__global__ __launch_bounds__(256)
void convert_w(const float* __restrict__ Wc, const float* __restrict__ Wt,
               const float* __restrict__ Wl, const float* __restrict__ Wg,
               const float* __restrict__ Wo, const float* __restrict__ Wp,
               u16* __restrict__ dst)
{
    __shared__ float L[64][65];
    const int t   = threadIdx.x;
    const int mid = blockIdx.x >> 10;
    const int tb  = blockIdx.x & 1023;
    u16* out = dst + (size_t)mid * WMAT_ELEMS;
    if (mid < 5) {
        const float* src = (mid == 0) ? Wc : (mid == 1) ? Wt : (mid == 2) ? Wl
                         : (mid == 3) ? Wg : Wo;
        const size_t base = (size_t)tb * 4096 + (size_t)t * 16;
#pragma unroll
        for (int i = 0; i < 2; ++i) {
            float4 a = *(const float4*)(src + base + i * 8);
            float4 b = *(const float4*)(src + base + i * 8 + 4);
            short8 s;
            s[0] = (short)f2bf(a.x); s[1] = (short)f2bf(a.y);
            s[2] = (short)f2bf(a.z); s[3] = (short)f2bf(a.w);
            s[4] = (short)f2bf(b.x); s[5] = (short)f2bf(b.y);
            s[6] = (short)f2bf(b.z); s[7] = (short)f2bf(b.w);
            *(short8*)(out + base + i * 8) = s;
        }
    } else {
        const float* src = (mid == 5) ? Wp : Wl;
        const int k0 = (tb & 31) * 64;
        const int o0 = (tb >> 5) * 64;
        const int row = t >> 2;          // source k-row 0..63
        const int cq  = t & 3;           // 16-col quad
#pragma unroll
        for (int i = 0; i < 4; ++i) {
            float4 v = *(const float4*)(src + (size_t)(k0 + row) * Hdim + o0 + cq * 16 + i * 4);
            *(float4*)(&L[row][cq * 16 + i * 4]) = v;
        }
        __syncthreads();
        const int orow = t >> 2;         // dest o-row 0..63
#pragma unroll
        for (int half = 0; half < 2; ++half) {
            short8 s;
#pragma unroll
            for (int i = 0; i < 8; ++i)
                s[i] = (short)f2bf(L[cq * 16 + half * 8 + i][orow]);
            *(short8*)(out + (size_t)(o0 + orow) * Hdim + k0 + cq * 16 + half * 8) = s;
        }
    }
}

// MFMA GEMV: part[ks][b][o] = sum_{k in ks-range} X[b,k] * Wb[o][k]
// X f32 [64][2048] (converted to bf16 while staging); Wb bf16 [o][k].
// Grid 512 = 8 k-splits x 64 o-tiles(32). 2 blocks/CU, 8 waves/CU (R6-proven
// core, geometry widened for latency hiding). No launch_bounds cap (R5), no
// consumer-side sums (R4/R8/R10), no fences/barriers (R3/R11).
__global__ __launch_bounds__(256)
void mfma_gemv(const float* __restrict__ X, const u16* __restrict__ Wb,
               float* __restrict__ part)
{
    __shared__ short Xs[64][72];   // row stride 144B -> conflict-benign
    __shared__ short Ws[32][72];
    const int t  = threadIdx.x;
    const int nt = blockIdx.x & 63;
    const int ks = blockIdx.x >> 6;
    const int o0 = nt * 32;
    const int kb = ks * 256;
    const int wv = t >> 6;
    const int ln = t & 63;
    const int xr = t & 63;            // X stage: row
    const int xc = (t >> 6) * 16;     // X stage: 16-col group
    const int wn = t >> 3;            // W stage: o-row 0..31
    const int wk = (t & 7) * 8;       // W stage: 8-k group (16B)

    f32x4 acc[2];
#pragma unroll
    for (int i = 0; i < 2; ++i)
#pragma unroll
        for (int j = 0; j < 4; ++j) acc[i][j] = 0.f;

    float4 px[4];
    uint4  pw;
    auto gload = [&](int k0) {
#pragma unroll
        for (int i = 0; i < 4; ++i)
            px[i] = *(const float4*)(X + (size_t)xr * Hdim + k0 + xc + i * 4);
        pw = *(const uint4*)(Wb + (size_t)(o0 + wn) * Hdim + k0 + wk);
    };
    auto lstore = [&]() {
#pragma unroll
        for (int i = 0; i < 2; ++i) {
            short8 s;
            s[0] = (short)f2bf(px[i*2].x);   s[1] = (short)f2bf(px[i*2].y);
            s[2] = (short)f2bf(px[i*2].z);   s[3] = (short)f2bf(px[i*2].w);
            s[4] = (short)f2bf(px[i*2+1].x); s[5] = (short)f2bf(px[i*2+1].y);
            s[6] = (short)f2bf(px[i*2+1].z); s[7] = (short)f2bf(px[i*2+1].w);
            *(short8*)(&Xs[xr][xc + i * 8]) = s;
        }
        *(uint4*)(&Ws[wn][wk]) = pw;
    };

    gload(kb);
    for (int c = 0; c < 4; ++c) {
        __syncthreads();
        lstore();
        __syncthreads();
        if (c < 3) gload(kb + (c + 1) * 64);
#pragma unroll
        for (int kstep = 0; kstep < 2; ++kstep) {
            const int kf = kstep * 32 + (ln >> 4) * 8;
            short8 af = *(const short8*)(&Xs[16 * wv + (ln & 15)][kf]);
#pragma unroll
            for (int n4 = 0; n4 < 2; ++n4) {
                short8 bf = *(const short8*)(&Ws[n4 * 16 + (ln & 15)][kf]);
                acc[n4] = __builtin_amdgcn_mfma_f32_16x16x32_bf16(af, bf, acc[n4], 0, 0, 0);
            }
        }
    }
#pragma unroll
    for (int n4 = 0; n4 < 2; ++n4) {
#pragma unroll
        for (int r = 0; r < 4; ++r) {
            const int brow = 16 * wv + (ln >> 4) * 4 + r;
            part[(size_t)(ks * 64 + brow) * Hdim + o0 + n4 * 16 + (ln & 15)] = acc[n4][r];
        }
    }
}

// Y[b,o] (=|+=) sum_s part[s][b][o] (+ bias[o]); optionally also write out.
// Grid 256, float2/thread (doubled parallelism for the latency-bound 8-deep sum).
template<int HASBIAS, int ACC, int FINAL>
__global__ __launch_bounds__(256)
void combine(const float* __restrict__ part, const float* __restrict__ bias,
             float* __restrict__ Y, float* __restrict__ out, int has_loss)
{
    const int flat2 = blockIdx.x * 256 + threadIdx.x;   // 0..65535
    const size_t e  = (size_t)flat2 * 2;
    const int o     = (int)(e & (Hdim - 1));
    float2 v;
    if (HASBIAS) v = *(const float2*)(bias + o);
    else         v = make_float2(0.f, 0.f);
#pragma unroll
    for (int s = 0; s < KSPLIT; ++s) {
        float2 p = *(const float2*)(part + (size_t)s * (64 * Hdim) + e);
        v.x += p.x; v.y += p.y;
    }
    if (ACC) {
        float2 a = *(const float2*)(Y + e);
        v.x += a.x; v.y += a.y;
    }
    *(float2*)(Y + e) = v;
    if (FINAL) {
        *(float2*)(out + e) = v;
        if (has_loss && flat2 == 0) out[Bdim * Hdim] = 0.f;
    }
}

// One (b, 8-row n-chunk): scores -> local softmax -> partial weighted sum.
// FIRST: read f32 lfb and also write bf16 cache; else read bf16 cache.
template<int FIRST>
__global__ __launch_bounds__(256, 4)
void flash_chunk(const float* __restrict__ lfb, const u16* __restrict__ lfb16r,
                 u16* __restrict__ lfb16w, const float* __restrict__ thetal,
                 float scale, u16* __restrict__ up,
                 float* __restrict__ wm, float* __restrict__ wz)
{
    __shared__ u16 T[NCHUNK][Hdim];   // 32 KB
    __shared__ float th[Hdim];        // 8 KB
    __shared__ float sc[NCHUNK];
    __shared__ float wts[NCHUNK];
    const int t  = threadIdx.x;
    const int b  = blockIdx.x >> 6;
    const int ch = blockIdx.x & 63;
    const size_t nbase = (size_t)b * Ndim + ch * NCHUNK;
#pragma unroll
    for (int i = 0; i < 16; ++i) {
        int flat4 = i * 256 + t;
        int row   = flat4 >> 9;
        int c4    = flat4 & 511;
        if (FIRST) {
            float4 v = *(const float4*)(lfb + (nbase + row) * Hdim + c4 * 4);
            ushort4 u4;
            u4.x = f2bf(v.x); u4.y = f2bf(v.y); u4.z = f2bf(v.z); u4.w = f2bf(v.w);
            *(ushort4*)(&T[row][c4 * 4]) = u4;
            *(ushort4*)(lfb16w + (nbase + row) * Hdim + c4 * 4) = u4;
        } else {
            ushort4 u4 = *(const ushort4*)(lfb16r + (nbase + row) * Hdim + c4 * 4);
            *(ushort4*)(&T[row][c4 * 4]) = u4;
        }
    }
#pragma unroll
    for (int i = 0; i < 2; ++i) {
        int c = (i * 256 + t) * 4;
        float4 v = *(const float4*)(thetal + (size_t)b * Hdim + c);
        *(float4*)(&th[c]) = v;
    }
    __syncthreads();
    const int wv = t >> 6, ln = t & 63;
#pragma unroll
    for (int q = 0; q < 2; ++q) {
        int n = wv * 2 + q;
        float a = 0.f;
#pragma unroll
        for (int i = 0; i < 8; ++i) {
            int c = ln * 4 + i * 256;
            ushort4 x = *(const ushort4*)(&T[n][c]);
            float4 y  = *(const float4*)(&th[c]);
            a += bf2f(x.x) * y.x + bf2f(x.y) * y.y + bf2f(x.z) * y.z + bf2f(x.w) * y.w;
        }
#pragma unroll
        for (int off = 32; off; off >>= 1) a += __shfl_xor(a, off, 64);
        if (ln == 0) sc[n] = a * scale;
    }
    __syncthreads();
    float m = sc[0];
#pragma unroll
    for (int n = 1; n < NCHUNK; ++n) m = fmaxf(m, sc[n]);
    if (t < NCHUNK) wts[t] = expf(sc[t] - m);
    __syncthreads();
    if (t == 0) {
        float z = 0.f;
#pragma unroll
        for (int n = 0; n < NCHUNK; ++n) z += wts[n];
        wm[blockIdx.x] = m;
        wz[blockIdx.x] = z;
    }
#pragma unroll
    for (int i = 0; i < 8; ++i) {
        int c = t + i * 256;
        float a = 0.f;
#pragma unroll
        for (int n = 0; n < NCHUNK; ++n) a += wts[n] * bf2f(T[n][c]);
        up[(size_t)blockIdx.x * Hdim + c] = f2bf(a);
    }
}

__global__ __launch_bounds__(256)
void flash_comb(const u16* __restrict__ up, const float* __restrict__ wm,
                const float* __restrict__ wz, float* __restrict__ u)
{
    __shared__ float mm[64], zz[64], ee[64];
    const int t  = threadIdx.x;
    const int b  = blockIdx.x >> 3;
    const int sl = blockIdx.x & 7;
    if (t < 64) { mm[t] = wm[b * 64 + t]; zz[t] = wz[b * 64 + t]; }
    __syncthreads();
    float mg = mm[0];
#pragma unroll
    for (int i = 1; i < 64; ++i) mg = fmaxf(mg, mm[i]);
    if (t < 64) ee[t] = expf(mm[t] - mg);
    __syncthreads();
    float Z = 0.f;
#pragma unroll
    for (int i = 0; i < 64; ++i) Z += zz[i] * ee[i];
    const float inv = 1.f / Z;
    const int col = sl * 256 + t;
    float a = 0.f;
#pragma unroll 8
    for (int ch = 0; ch < 64; ++ch)
        a += ee[ch] * bf2f(up[(size_t)(b * 64 + ch) * Hdim + col]);
    u[(size_t)b * Hdim + col] = a * inv;
}

// r = relu(layernorm(sum_s part[s][b][:] + bias))   (64-block consumer-sum:
// small-grid partial read is proven fine — 4 MB total)
__global__ __launch_bounds__(256)
void ln_relu_part(const float* __restrict__ part, const float* __restrict__ bias,
                  float* __restrict__ r)
{
    __shared__ float trow[Hdim];
    __shared__ float red[8];
    const int t = threadIdx.x, b = blockIdx.x;
    float sum = 0.f, sq = 0.f;
#pragma unroll
    for (int i = 0; i < 2; ++i) {
        int c = (i * 256 + t) * 4;
        float4 v = *(const float4*)(bias + c);
#pragma unroll
        for (int s = 0; s < KSPLIT; ++s) {
            float4 p = *(const float4*)(part + ((size_t)(s * 64 + b)) * Hdim + c);
            v.x += p.x; v.y += p.y; v.z += p.z; v.w += p.w;
        }
        *(float4*)(&trow[c]) = v;
        sum += v.x + v.y + v.z + v.w;
        sq  += v.x * v.x + v.y * v.y + v.z * v.z + v.w * v.w;
    }
#pragma unroll
    for (int off = 32; off; off >>= 1) {
        sum += __shfl_xor(sum, off, 64);
        sq  += __shfl_xor(sq,  off, 64);
    }
    if ((t & 63) == 0) { red[t >> 6] = sum; red[4 + (t >> 6)] = sq; }
    __syncthreads();
    sum = red[0] + red[1] + red[2] + red[3];
    sq  = red[4] + red[5] + red[6] + red[7];
    const float mu   = sum * (1.f / Hdim);
    const float var  = sq * (1.f / Hdim) - mu * mu;
    const float rstd = rsqrtf(var + LNEPS);
#pragma unroll
    for (int i = 0; i < 2; ++i) {
        int c = (i * 256 + t) * 4;
        float4 v = *(const float4*)(&trow[c]);
        float4 o;
        o.x = fmaxf(0.f, (v.x - mu) * rstd);
        o.y = fmaxf(0.f, (v.y - mu) * rstd);
        o.z = fmaxf(0.f, (v.z - mu) * rstd);
        o.w = fmaxf(0.f, (v.w - mu) * rstd);
        *(float4*)(r + (size_t)b * Hdim + c) = o;
    }
}

extern "C" void kernel_launch(void* const* d_in, const int* in_sizes, int n_in,
                              void* d_out, int out_size, void* d_ws, size_t ws_size,
                              hipStream_t stream) {
    (void)in_sizes; (void)n_in; (void)ws_size;
    const float* clip = (const float*)d_in[0];
    const float* lfb  = (const float*)d_in[1];
    const float* Wc   = (const float*)d_in[2];
    const float* bc   = (const float*)d_in[3];
    const float* Wl   = (const float*)d_in[4];
    const float* bl   = (const float*)d_in[5];
    const float* Wt   = (const float*)d_in[6];
    const float* bt   = (const float*)d_in[7];
    const float* Wp   = (const float*)d_in[8];
    // d_in[9] = bp: cancels in softmax (per-row constant) -> unused
    const float* Wg   = (const float*)d_in[10];
    const float* bg   = (const float*)d_in[11];
    const float* Wo   = (const float*)d_in[12];
    const float* bo   = (const float*)d_in[13];
    float* out = (float*)d_out;

    // Workspace layout in f32 slots; u16 buffers counted in f32 slots.
    float* wsf    = (float*)d_ws;
    float* A      = wsf;
    float* theta  = wsf + 131072;
    float* thetap = wsf + 262144;
    float* thetal = wsf + 393216;
    float* u      = wsf + 524288;
    float* r      = wsf + 655360;
    float* PA     = wsf + 786432;            // 8*64*2048 = 1048576 -> end 1835008
    float* wm     = wsf + 1835008;           // 4096
    float* wz     = wsf + 1839104;           // 4096
    u16*   up     = (u16*)(wsf + 1843200);   // 4194304 f32 slots -> end 6037504
    u16*   lfb16  = (u16*)(wsf + 6037504);   // 33554432 f32 slots -> end 39591936
    u16*   Wbf    = (u16*)(wsf + 39591936);  // 7 * 2097152 f32 slots (~217 MB total)

    u16* bWc  = Wbf + (size_t)0 * WMAT_ELEMS;
    u16* bWt  = Wbf + (size_t)1 * WMAT_ELEMS;
    u16* bWl  = Wbf + (size_t)2 * WMAT_ELEMS;
    u16* bWg  = Wbf + (size_t)3 * WMAT_ELEMS;
    u16* bWo  = Wbf + (size_t)4 * WMAT_ELEMS;
    u16* bWpT = Wbf + (size_t)5 * WMAT_ELEMS;
    u16* bWlT = Wbf + (size_t)6 * WMAT_ELEMS;

    const float scale = 0.022097086912079608f;   // 1/sqrt(2048)
    dim3 blk(256);
    const int has_loss = (out_size > Bdim * Hdim) ? 1 : 0;

    // one-time: bf16 weight views
    convert_w<<<7168, blk, 0, stream>>>(Wc, Wt, Wl, Wg, Wo, Wp, Wbf);

    // A = clip @ Wc^T + bc
    mfma_gemv<<<512, blk, 0, stream>>>(clip, bWc, PA);
    combine<1,0,0><<<256, blk, 0, stream>>>(PA, bc, A, nullptr, 0);

    for (int l = 0; l < 3; ++l) {
        // theta = A @ Wt^T + bt
        mfma_gemv<<<512, blk, 0, stream>>>(A, bWt, PA);
        combine<1,0,0><<<256, blk, 0, stream>>>(PA, bt, theta, nullptr, 0);
        // thetap = theta @ Wp
        mfma_gemv<<<512, blk, 0, stream>>>(theta, bWpT, PA);
        combine<0,0,0><<<256, blk, 0, stream>>>(PA, nullptr, thetap, nullptr, 0);
        // thetal = thetap @ Wl
        mfma_gemv<<<512, blk, 0, stream>>>(thetap, bWlT, PA);
        combine<0,0,0><<<256, blk, 0, stream>>>(PA, nullptr, thetal, nullptr, 0);
        // fused scores/softmax/weighted-sum over lfb
        if (l == 0)
            flash_chunk<1><<<4096, blk, 0, stream>>>(lfb, nullptr, lfb16, thetal, scale, up, wm, wz);
        else
            flash_chunk<0><<<4096, blk, 0, stream>>>(nullptr, lfb16, nullptr, thetal, scale, up, wm, wz);
        flash_comb<<<512, blk, 0, stream>>>(up, wm, wz, u);
        // s = u @ Wl^T + bl
        mfma_gemv<<<512, blk, 0, stream>>>(u, bWl, PA);
        combine<1,0,0><<<256, blk, 0, stream>>>(PA, bl, theta, nullptr, 0);
        // t = s @ Wg^T + bg (bg added in LN kernel); r = relu(LN(t))
        mfma_gemv<<<512, blk, 0, stream>>>(theta, bWg, PA);
        ln_relu_part<<<64, blk, 0, stream>>>(PA, bg, r);
        // A += r @ Wo^T + bo   (last layer also writes out + loss)
        mfma_gemv<<<512, blk, 0, stream>>>(r, bWo, PA);
        if (l < 2)
            combine<1,1,0><<<256, blk, 0, stream>>>(PA, bo, A, nullptr, 0);
        else
            combine<1,1,1><<<256, blk, 0, stream>>>(PA, bo, A, out, has_loss);
    }
}

// Round 13
// 382.259 us; speedup vs baseline: 3.3190x; 1.0224x over previous
//
#include <hip/hip_runtime.h>

#define Bdim 64
#define Ndim 512
#define Hdim 2048
#define KSPLIT 8
#define NCHUNK 8
#define LNEPS 1e-5f
#define WMAT_ELEMS (Hdim * Hdim)

typedef unsigned short u16;
typedef __attribute__((ext_vector_type(8))) short short8;
typedef __attribute__((ext_vector_type(4))) float f32x4;

__device__ __forceinline__ u16 f2bf(float f) {
    unsigned int u = __float_as_uint(f);
    return (u16)((u + 0x7FFFu + ((u >> 16) & 1u)) >> 16);
}
__device__ __forceinline__ float bf2f(u16 s) {
    return __uint_as_float(((unsigned int)s) << 16);
}

// Shared gemv body (R12-proven geometry): part[ks][b][o] = sum_k X[b,k]*W[o][k]
// over k-slice ks. vbid in [0,512) = 8 ks x 64 o-tiles(32). X always f32
// (bf16-converted during staging); W bf16 (WF32=0) or f32 inline (WF32=1).
template<int WF32>
__device__ __forceinline__
void gemv_body(int vbid, const float* __restrict__ X, const u16* __restrict__ Wb,
               const float* __restrict__ Wf, float* __restrict__ part, char* smRaw)
{
    short (*Xs)[72] = (short(*)[72])smRaw;                    // 9216 B
    short (*Ws)[72] = (short(*)[72])(smRaw + 64 * 72 * 2);    // 4608 B
    const int t  = threadIdx.x;
    const int nt = vbid & 63;
    const int ks = vbid >> 6;
    const int o0 = nt * 32;
    const int kb = ks * 256;
    const int wv = t >> 6;
    const int ln = t & 63;
    const int xr = t & 63;            // X stage: row
    const int xc = (t >> 6) * 16;     // X stage: 16-col group
    const int wn = t >> 3;            // W stage: o-row 0..31
    const int wk = (t & 7) * 8;       // W stage: 8-k group

    f32x4 acc[2];
#pragma unroll
    for (int i = 0; i < 2; ++i)
#pragma unroll
        for (int j = 0; j < 4; ++j) acc[i][j] = 0.f;

    float4 px[4];
    uint4  qw;
    float4 pw[2];
    auto gload = [&](int k0) {
#pragma unroll
        for (int i = 0; i < 4; ++i)
            px[i] = *(const float4*)(X + (size_t)xr * Hdim + k0 + xc + i * 4);
        if (!WF32) {
            qw = *(const uint4*)(Wb + (size_t)(o0 + wn) * Hdim + k0 + wk);
        } else {
            pw[0] = *(const float4*)(Wf + (size_t)(o0 + wn) * Hdim + k0 + wk);
            pw[1] = *(const float4*)(Wf + (size_t)(o0 + wn) * Hdim + k0 + wk + 4);
        }
    };
    auto cvt8 = [](const float4& a, const float4& b) {
        short8 s;
        s[0] = (short)f2bf(a.x); s[1] = (short)f2bf(a.y);
        s[2] = (short)f2bf(a.z); s[3] = (short)f2bf(a.w);
        s[4] = (short)f2bf(b.x); s[5] = (short)f2bf(b.y);
        s[6] = (short)f2bf(b.z); s[7] = (short)f2bf(b.w);
        return s;
    };
    auto lstore = [&]() {
        *(short8*)(&Xs[xr][xc])     = cvt8(px[0], px[1]);
        *(short8*)(&Xs[xr][xc + 8]) = cvt8(px[2], px[3]);
        if (!WF32) *(uint4*)(&Ws[wn][wk]) = qw;
        else       *(short8*)(&Ws[wn][wk]) = cvt8(pw[0], pw[1]);
    };

    gload(kb);
    for (int c = 0; c < 4; ++c) {
        __syncthreads();
        lstore();
        __syncthreads();
        if (c < 3) gload(kb + (c + 1) * 64);
#pragma unroll
        for (int kstep = 0; kstep < 2; ++kstep) {
            const int kf = kstep * 32 + (ln >> 4) * 8;
            short8 af = *(const short8*)(&Xs[16 * wv + (ln & 15)][kf]);
#pragma unroll
            for (int n4 = 0; n4 < 2; ++n4) {
                short8 bf = *(const short8*)(&Ws[n4 * 16 + (ln & 15)][kf]);
                acc[n4] = __builtin_amdgcn_mfma_f32_16x16x32_bf16(af, bf, acc[n4], 0, 0, 0);
            }
        }
    }
#pragma unroll
    for (int n4 = 0; n4 < 2; ++n4) {
#pragma unroll
        for (int r = 0; r < 4; ++r) {
            const int brow = 16 * wv + (ln >> 4) * 4 + r;
            part[(size_t)(ks * 64 + brow) * Hdim + o0 + n4 * 16 + (ln & 15)] = acc[n4][r];
        }
    }
}

// One-time prep + A-prologue fused (independent work, disjoint outputs):
// bid [0,4096):    direct convert Wt,Wl,Wg,Wo -> mids 0..3
// bid [4096,6144): transpose-convert Wp,Wl -> bWpT(4), bWlT(5)
// bid [6144,6656): A-gemv partials = clip @ Wc^T (both f32, inline convert)
__global__ __launch_bounds__(256)
void convert_w(const float* __restrict__ Wt, const float* __restrict__ Wl,
               const float* __restrict__ Wg, const float* __restrict__ Wo,
               const float* __restrict__ Wp, const float* __restrict__ clip,
               const float* __restrict__ Wc, u16* __restrict__ dst,
               float* __restrict__ partA)
{
    __shared__ char SM[16640];          // max(transpose L 64x65 f32, gemv tiles)
    const int t   = threadIdx.x;
    const int bid = blockIdx.x;
    if (bid < 4096) {
        const int mid = bid >> 10;
        const int tb  = bid & 1023;
        const float* src = (mid == 0) ? Wt : (mid == 1) ? Wl : (mid == 2) ? Wg : Wo;
        u16* out = dst + (size_t)mid * WMAT_ELEMS;
        const size_t base = (size_t)tb * 4096 + (size_t)t * 16;
#pragma unroll
        for (int i = 0; i < 2; ++i) {
            float4 a = *(const float4*)(src + base + i * 8);
            float4 b = *(const float4*)(src + base + i * 8 + 4);
            short8 s;
            s[0] = (short)f2bf(a.x); s[1] = (short)f2bf(a.y);
            s[2] = (short)f2bf(a.z); s[3] = (short)f2bf(a.w);
            s[4] = (short)f2bf(b.x); s[5] = (short)f2bf(b.y);
            s[6] = (short)f2bf(b.z); s[7] = (short)f2bf(b.w);
            *(short8*)(out + base + i * 8) = s;
        }
    } else if (bid < 6144) {
        float (*L)[65] = (float(*)[65])SM;
        const int mid = 4 + ((bid - 4096) >> 10);
        const int tb  = (bid - 4096) & 1023;
        const float* src = (mid == 4) ? Wp : Wl;
        u16* out = dst + (size_t)mid * WMAT_ELEMS;
        const int k0 = (tb & 31) * 64;
        const int o0 = (tb >> 5) * 64;
        const int row = t >> 2;
        const int cq  = t & 3;
#pragma unroll
        for (int i = 0; i < 4; ++i) {
            float4 v = *(const float4*)(src + (size_t)(k0 + row) * Hdim + o0 + cq * 16 + i * 4);
            *(float4*)(&L[row][cq * 16 + i * 4]) = v;
        }
        __syncthreads();
        const int orow = t >> 2;
#pragma unroll
        for (int half = 0; half < 2; ++half) {
            short8 s;
#pragma unroll
            for (int i = 0; i < 8; ++i)
                s[i] = (short)f2bf(L[cq * 16 + half * 8 + i][orow]);
            *(short8*)(out + (size_t)(o0 + orow) * Hdim + k0 + cq * 16 + half * 8) = s;
        }
    } else {
        gemv_body<1>(bid - 6144, clip, nullptr, Wc, partA, SM);
    }
}

// MFMA GEMV node (bf16 W). Grid 512 = 8 ks x 64 o-tiles(32), 2 blocks/CU.
// No launch_bounds cap (R5), no consumer-side sums (R4/R8/R10), no
// fences/barriers (R3/R11).
__global__ __launch_bounds__(256)
void mfma_gemv(const float* __restrict__ X, const u16* __restrict__ Wb,
               float* __restrict__ part)
{
    __shared__ char SM[13824];
    gemv_body<0>(blockIdx.x, X, Wb, nullptr, part, SM);
}

// Y[b,o] (=|+=) sum_s part[s][b][o] (+ bias[o]); optionally also write out.
// Grid 256, float2/thread.
template<int HASBIAS, int ACC, int FINAL>
__global__ __launch_bounds__(256)
void combine(const float* __restrict__ part, const float* __restrict__ bias,
             float* __restrict__ Y, float* __restrict__ out, int has_loss)
{
    const int flat2 = blockIdx.x * 256 + threadIdx.x;   // 0..65535
    const size_t e  = (size_t)flat2 * 2;
    const int o     = (int)(e & (Hdim - 1));
    float2 v;
    if (HASBIAS) v = *(const float2*)(bias + o);
    else         v = make_float2(0.f, 0.f);
#pragma unroll
    for (int s = 0; s < KSPLIT; ++s) {
        float2 p = *(const float2*)(part + (size_t)s * (64 * Hdim) + e);
        v.x += p.x; v.y += p.y;
    }
    if (ACC) {
        float2 a = *(const float2*)(Y + e);
        v.x += a.x; v.y += a.y;
    }
    *(float2*)(Y + e) = v;
    if (FINAL) {
        *(float2*)(out + e) = v;
        if (has_loss && flat2 == 0) out[Bdim * Hdim] = 0.f;
    }
}

// One (b, 8-row n-chunk): scores -> local softmax -> partial weighted sum.
// FIRST: read f32 lfb and also write bf16 cache; else read bf16 cache.
template<int FIRST>
__global__ __launch_bounds__(256, 4)
void flash_chunk(const float* __restrict__ lfb, const u16* __restrict__ lfb16r,
                 u16* __restrict__ lfb16w, const float* __restrict__ thetal,
                 float scale, u16* __restrict__ up,
                 float* __restrict__ wm, float* __restrict__ wz)
{
    __shared__ u16 T[NCHUNK][Hdim];   // 32 KB
    __shared__ float th[Hdim];        // 8 KB
    __shared__ float sc[NCHUNK];
    __shared__ float wts[NCHUNK];
    const int t  = threadIdx.x;
    const int b  = blockIdx.x >> 6;
    const int ch = blockIdx.x & 63;
    const size_t nbase = (size_t)b * Ndim + ch * NCHUNK;
#pragma unroll
    for (int i = 0; i < 16; ++i) {
        int flat4 = i * 256 + t;
        int row   = flat4 >> 9;
        int c4    = flat4 & 511;
        if (FIRST) {
            float4 v = *(const float4*)(lfb + (nbase + row) * Hdim + c4 * 4);
            ushort4 u4;
            u4.x = f2bf(v.x); u4.y = f2bf(v.y); u4.z = f2bf(v.z); u4.w = f2bf(v.w);
            *(ushort4*)(&T[row][c4 * 4]) = u4;
            *(ushort4*)(lfb16w + (nbase + row) * Hdim + c4 * 4) = u4;
        } else {
            ushort4 u4 = *(const ushort4*)(lfb16r + (nbase + row) * Hdim + c4 * 4);
            *(ushort4*)(&T[row][c4 * 4]) = u4;
        }
    }
#pragma unroll
    for (int i = 0; i < 2; ++i) {
        int c = (i * 256 + t) * 4;
        float4 v = *(const float4*)(thetal + (size_t)b * Hdim + c);
        *(float4*)(&th[c]) = v;
    }
    __syncthreads();
    const int wv = t >> 6, ln = t & 63;
#pragma unroll
    for (int q = 0; q < 2; ++q) {
        int n = wv * 2 + q;
        float a = 0.f;
#pragma unroll
        for (int i = 0; i < 8; ++i) {
            int c = ln * 4 + i * 256;
            ushort4 x = *(const ushort4*)(&T[n][c]);
            float4 y  = *(const float4*)(&th[c]);
            a += bf2f(x.x) * y.x + bf2f(x.y) * y.y + bf2f(x.z) * y.z + bf2f(x.w) * y.w;
        }
#pragma unroll
        for (int off = 32; off; off >>= 1) a += __shfl_xor(a, off, 64);
        if (ln == 0) sc[n] = a * scale;
    }
    __syncthreads();
    float m = sc[0];
#pragma unroll
    for (int n = 1; n < NCHUNK; ++n) m = fmaxf(m, sc[n]);
    if (t < NCHUNK) wts[t] = expf(sc[t] - m);
    __syncthreads();
    if (t == 0) {
        float z = 0.f;
#pragma unroll
        for (int n = 0; n < NCHUNK; ++n) z += wts[n];
        wm[blockIdx.x] = m;
        wz[blockIdx.x] = z;
    }
#pragma unroll
    for (int i = 0; i < 8; ++i) {
        int c = t + i * 256;
        float a = 0.f;
#pragma unroll
        for (int n = 0; n < NCHUNK; ++n) a += wts[n] * bf2f(T[n][c]);
        up[(size_t)blockIdx.x * Hdim + c] = f2bf(a);
    }
}

__global__ __launch_bounds__(256)
void flash_comb(const u16* __restrict__ up, const float* __restrict__ wm,
                const float* __restrict__ wz, float* __restrict__ u)
{
    __shared__ float mm[64], zz[64], ee[64];
    const int t  = threadIdx.x;
    const int b  = blockIdx.x >> 3;
    const int sl = blockIdx.x & 7;
    if (t < 64) { mm[t] = wm[b * 64 + t]; zz[t] = wz[b * 64 + t]; }
    __syncthreads();
    float mg = mm[0];
#pragma unroll
    for (int i = 1; i < 64; ++i) mg = fmaxf(mg, mm[i]);
    if (t < 64) ee[t] = expf(mm[t] - mg);
    __syncthreads();
    float Z = 0.f;
#pragma unroll
    for (int i = 0; i < 64; ++i) Z += zz[i] * ee[i];
    const float inv = 1.f / Z;
    const int col = sl * 256 + t;
    float a = 0.f;
#pragma unroll 8
    for (int ch = 0; ch < 64; ++ch)
        a += ee[ch] * bf2f(up[(size_t)(b * 64 + ch) * Hdim + col]);
    u[(size_t)b * Hdim + col] = a * inv;
}

// r = relu(layernorm(sum_s part[s][b][:] + bias))
__global__ __launch_bounds__(256)
void ln_relu_part(const float* __restrict__ part, const float* __restrict__ bias,
                  float* __restrict__ r)
{
    __shared__ float trow[Hdim];
    __shared__ float red[8];
    const int t = threadIdx.x, b = blockIdx.x;
    float sum = 0.f, sq = 0.f;
#pragma unroll
    for (int i = 0; i < 2; ++i) {
        int c = (i * 256 + t) * 4;
        float4 v = *(const float4*)(bias + c);
#pragma unroll
        for (int s = 0; s < KSPLIT; ++s) {
            float4 p = *(const float4*)(part + ((size_t)(s * 64 + b)) * Hdim + c);
            v.x += p.x; v.y += p.y; v.z += p.z; v.w += p.w;
        }
        *(float4*)(&trow[c]) = v;
        sum += v.x + v.y + v.z + v.w;
        sq  += v.x * v.x + v.y * v.y + v.z * v.z + v.w * v.w;
    }
#pragma unroll
    for (int off = 32; off; off >>= 1) {
        sum += __shfl_xor(sum, off, 64);
        sq  += __shfl_xor(sq,  off, 64);
    }
    if ((t & 63) == 0) { red[t >> 6] = sum; red[4 + (t >> 6)] = sq; }
    __syncthreads();
    sum = red[0] + red[1] + red[2] + red[3];
    sq  = red[4] + red[5] + red[6] + red[7];
    const float mu   = sum * (1.f / Hdim);
    const float var  = sq * (1.f / Hdim) - mu * mu;
    const float rstd = rsqrtf(var + LNEPS);
#pragma unroll
    for (int i = 0; i < 2; ++i) {
        int c = (i * 256 + t) * 4;
        float4 v = *(const float4*)(&trow[c]);
        float4 o;
        o.x = fmaxf(0.f, (v.x - mu) * rstd);
        o.y = fmaxf(0.f, (v.y - mu) * rstd);
        o.z = fmaxf(0.f, (v.z - mu) * rstd);
        o.w = fmaxf(0.f, (v.w - mu) * rstd);
        *(float4*)(r + (size_t)b * Hdim + c) = o;
    }
}

extern "C" void kernel_launch(void* const* d_in, const int* in_sizes, int n_in,
                              void* d_out, int out_size, void* d_ws, size_t ws_size,
                              hipStream_t stream) {
    (void)in_sizes; (void)n_in; (void)ws_size;
    const float* clip = (const float*)d_in[0];
    const float* lfb  = (const float*)d_in[1];
    const float* Wc   = (const float*)d_in[2];
    const float* bc   = (const float*)d_in[3];
    const float* Wl   = (const float*)d_in[4];
    const float* bl   = (const float*)d_in[5];
    const float* Wt   = (const float*)d_in[6];
    const float* bt   = (const float*)d_in[7];
    const float* Wp   = (const float*)d_in[8];
    // d_in[9] = bp: cancels in softmax (per-row constant) -> unused
    const float* Wg   = (const float*)d_in[10];
    const float* bg   = (const float*)d_in[11];
    const float* Wo   = (const float*)d_in[12];
    const float* bo   = (const float*)d_in[13];
    float* out = (float*)d_out;

    // Workspace layout in f32 slots; u16 buffers counted in f32 slots.
    float* wsf    = (float*)d_ws;
    float* A      = wsf;
    float* theta  = wsf + 131072;
    float* thetap = wsf + 262144;
    float* thetal = wsf + 393216;
    float* u      = wsf + 524288;
    float* r      = wsf + 655360;
    float* PA     = wsf + 786432;            // 8*64*2048 = 1048576 -> end 1835008
    float* wm     = wsf + 1835008;           // 4096
    float* wz     = wsf + 1839104;           // 4096
    u16*   up     = (u16*)(wsf + 1843200);   // 4194304 f32 slots -> end 6037504
    u16*   lfb16  = (u16*)(wsf + 6037504);   // 33554432 f32 slots -> end 39591936
    u16*   Wbf    = (u16*)(wsf + 39591936);  // 6 * 2097152 f32 slots (~208 MB)

    u16* bWt  = Wbf + (size_t)0 * WMAT_ELEMS;
    u16* bWl  = Wbf + (size_t)1 * WMAT_ELEMS;
    u16* bWg  = Wbf + (size_t)2 * WMAT_ELEMS;
    u16* bWo  = Wbf + (size_t)3 * WMAT_ELEMS;
    u16* bWpT = Wbf + (size_t)4 * WMAT_ELEMS;
    u16* bWlT = Wbf + (size_t)5 * WMAT_ELEMS;

    const float scale = 0.022097086912079608f;   // 1/sqrt(2048)
    dim3 blk(256);
    const int has_loss = (out_size > Bdim * Hdim) ? 1 : 0;

    // one-time: 6 bf16 weight views + A-prologue gemv fused (independent work)
    convert_w<<<6656, blk, 0, stream>>>(Wt, Wl, Wg, Wo, Wp, clip, Wc, Wbf, PA);
    combine<1,0,0><<<256, blk, 0, stream>>>(PA, bc, A, nullptr, 0);

    for (int l = 0; l < 3; ++l) {
        // theta = A @ Wt^T + bt
        mfma_gemv<<<512, blk, 0, stream>>>(A, bWt, PA);
        combine<1,0,0><<<256, blk, 0, stream>>>(PA, bt, theta, nullptr, 0);
        // thetap = theta @ Wp
        mfma_gemv<<<512, blk, 0, stream>>>(theta, bWpT, PA);
        combine<0,0,0><<<256, blk, 0, stream>>>(PA, nullptr, thetap, nullptr, 0);
        // thetal = thetap @ Wl
        mfma_gemv<<<512, blk, 0, stream>>>(thetap, bWlT, PA);
        combine<0,0,0><<<256, blk, 0, stream>>>(PA, nullptr, thetal, nullptr, 0);
        // fused scores/softmax/weighted-sum over lfb
        if (l == 0)
            flash_chunk<1><<<4096, blk, 0, stream>>>(lfb, nullptr, lfb16, thetal, scale, up, wm, wz);
        else
            flash_chunk<0><<<4096, blk, 0, stream>>>(nullptr, lfb16, nullptr, thetal, scale, up, wm, wz);
        flash_comb<<<512, blk, 0, stream>>>(up, wm, wz, u);
        // s = u @ Wl^T + bl
        mfma_gemv<<<512, blk, 0, stream>>>(u, bWl, PA);
        combine<1,0,0><<<256, blk, 0, stream>>>(PA, bl, theta, nullptr, 0);
        // t = s @ Wg^T + bg (bg added in LN kernel); r = relu(LN(t))
        mfma_gemv<<<512, blk, 0, stream>>>(theta, bWg, PA);
        ln_relu_part<<<64, blk, 0, stream>>>(PA, bg, r);
        // A += r @ Wo^T + bo   (last layer also writes out + loss)
        mfma_gemv<<<512, blk, 0, stream>>>(r, bWo, PA);
        if (l < 2)
            combine<1,1,0><<<256, blk, 0, stream>>>(PA, bo, A, nullptr, 0);
        else
            combine<1,1,1><<<256, blk, 0, stream>>>(PA, bo, A, out, has_loss);
    }
}